// Round 1
// baseline (23842.299 us; speedup 1.0000x reference)
//
#include <hip/hip_runtime.h>

#define NNODES 50000
#define HDIM 256
#define NLAYERS 4
#define NEDGES 800000
#define FIN 1280
#define LDOUT 1024

// ---------------------------------------------------------------------------
// GEMM: C[n, 0:256] = act( A[n,:K] @ W[K,256] + bias + (HAS_D ? D[n,:] : 0) )
// ACT: 0 none, 1 relu, 2 sigmoid.  A has row stride lda, C row stride ldc,
// D (if present) row stride 256.  64x64 tile, 256 threads, 4x4 microtile.
// ---------------------------------------------------------------------------
template<int ACT, bool HAS_D>
__global__ __launch_bounds__(256) void gemm_k(
    const float* __restrict__ A, int lda, int K,
    const float* __restrict__ W,
    const float* __restrict__ bias,
    const float* __restrict__ D,
    float* __restrict__ C, int ldc,
    int nrows)
{
    __shared__ float As[16][68];   // [k][row]
    __shared__ float Bs[16][68];   // [k][col]

    const int bx = blockIdx.x & 3;        // 4 col blocks (256/64)
    const int by = blockIdx.x >> 2;
    const int row0 = by * 64;
    const int col0 = bx * 64;
    const int tid = threadIdx.x;
    const int tx = tid & 15;
    const int ty = tid >> 4;

    float acc[4][4] = {};

    for (int k0 = 0; k0 < K; k0 += 16) {
        // A tile: 64 rows x 16 k.  thread t -> row t/4, k (t%4)*4
        {
            const int r = tid >> 2;
            const int c = (tid & 3) * 4;
            const int grow = row0 + r;
            float4 v = make_float4(0.f, 0.f, 0.f, 0.f);
            if (grow < nrows)
                v = *(const float4*)(A + (size_t)grow * lda + k0 + c);
            As[c + 0][r] = v.x; As[c + 1][r] = v.y;
            As[c + 2][r] = v.z; As[c + 3][r] = v.w;
        }
        // W tile: 16 k x 64 cols. thread t -> k t/16, col (t%16)*4
        {
            const int r = tid >> 4;
            const int c = (tid & 15) * 4;
            float4 v = *(const float4*)(W + (size_t)(k0 + r) * HDIM + col0 + c);
            Bs[r][c + 0] = v.x; Bs[r][c + 1] = v.y;
            Bs[r][c + 2] = v.z; Bs[r][c + 3] = v.w;
        }
        __syncthreads();
        #pragma unroll
        for (int k = 0; k < 16; ++k) {
            float a[4], b[4];
            #pragma unroll
            for (int i = 0; i < 4; ++i) a[i] = As[k][ty * 4 + i];
            #pragma unroll
            for (int j = 0; j < 4; ++j) b[j] = Bs[k][tx * 4 + j];
            #pragma unroll
            for (int i = 0; i < 4; ++i)
                #pragma unroll
                for (int j = 0; j < 4; ++j)
                    acc[i][j] += a[i] * b[j];
        }
        __syncthreads();
    }

    #pragma unroll
    for (int i = 0; i < 4; ++i) {
        const int grow = row0 + ty * 4 + i;
        if (grow < nrows) {
            #pragma unroll
            for (int j = 0; j < 4; ++j) {
                const int gcol = col0 + tx * 4 + j;
                float v = acc[i][j];
                if (bias) v += bias[gcol];
                if (HAS_D) v += D[(size_t)grow * HDIM + gcol];
                if (ACT == 1) v = fmaxf(v, 0.f);
                if (ACT == 2) v = 1.f / (1.f + expf(-v));
                C[(size_t)grow * ldc + gcol] = v;
            }
        }
    }
}

// ---------------------------------------------------------------------------
// scatter-add: out[dst[e], :] += rows[src[e], :]   (one wave per edge)
// ---------------------------------------------------------------------------
__global__ __launch_bounds__(256) void scatter_k(
    const float* __restrict__ rows,
    const int* __restrict__ srcIdx,
    const int* __restrict__ dstIdx,
    float* __restrict__ out)
{
    const int wave = (blockIdx.x * 256 + threadIdx.x) >> 6;
    const int lane = threadIdx.x & 63;
    if (wave >= NEDGES) return;
    const int s = srcIdx[wave];
    const int d = dstIdx[wave];
    const float4 v = *(const float4*)(rows + (size_t)s * HDIM + lane * 4);
    float* op = out + (size_t)d * HDIM + lane * 4;
    atomicAdd(op + 0, v.x);
    atomicAdd(op + 1, v.y);
    atomicAdd(op + 2, v.z);
    atomicAdd(op + 3, v.w);
}

// ---------------------------------------------------------------------------
// o[n,:] = x[n,:] * m[n,:]    (x has row stride ldx; m,o stride 256)
// ---------------------------------------------------------------------------
__global__ __launch_bounds__(256) void elemmul_k(
    const float* __restrict__ x, int ldx,
    const float* __restrict__ m,
    float* __restrict__ o)
{
    const int t = blockIdx.x * 256 + threadIdx.x;
    const int total = NNODES * (HDIM / 4);
    if (t >= total) return;
    const int row = t / (HDIM / 4);
    const int c = (t % (HDIM / 4)) * 4;
    const float4 xv = *(const float4*)(x + (size_t)row * ldx + c);
    const float4 mv = *(const float4*)(m + (size_t)row * HDIM + c);
    float4 r;
    r.x = xv.x * mv.x; r.y = xv.y * mv.y;
    r.z = xv.z * mv.z; r.w = xv.w * mv.w;
    *(float4*)(o + (size_t)row * HDIM + c) = r;
}

__global__ __launch_bounds__(256) void fill1_k(float* __restrict__ p, int n)
{
    const int t = blockIdx.x * 256 + threadIdx.x;
    if (t < n) p[t] = 1.0f;
}

// ---------------------------------------------------------------------------
extern "C" void kernel_launch(void* const* d_in, const int* in_sizes, int n_in,
                              void* d_out, int out_size, void* d_ws, size_t ws_size,
                              hipStream_t stream)
{
    const int*   edge   = (const int*)d_in[1];
    const int*   src    = edge;
    const int*   dst    = edge + NEDGES;
    const float* esm    = (const float*)d_in[2];
    const float* lin0_W = (const float*)d_in[4];
    const float* lin0_b = (const float*)d_in[5];
    const float* wc_W1  = (const float*)d_in[6];
    const float* wc_b1  = (const float*)d_in[7];
    const float* wc_W2  = (const float*)d_in[8];
    const float* wc_b2  = (const float*)d_in[9];
    const float* wc_W3  = (const float*)d_in[10];
    const float* wc_b3  = (const float*)d_in[11];
    const float* sc_Wn  = (const float*)d_in[12];
    const float* sc_bn  = (const float*)d_in[13];
    const float* sc_Wr  = (const float*)d_in[14];
    float* out = (float*)d_out;

    const size_t NH = (size_t)NNODES * HDIM;
    float* ws    = (float*)d_ws;
    float* x0    = ws;            // x after lin0
    float* maskb = ws + NH;       // mask_val
    float* bufA  = ws + 2 * NH;   // xm / xg
    float* bufB  = ws + 3 * NH;   // h_nb / h / tmp
    float* bufC  = ws + 4 * NH;   // agg

    const dim3 blk(256);
    const int rowBlocks = (NNODES + 63) / 64;
    const dim3 gemmGrid(rowBlocks * 4);
    const int emGrid = (NNODES * (HDIM / 4) + 255) / 256;
    const int scGrid = (NEDGES + 3) / 4;

    // x = esm @ lin0_W + lin0_b
    gemm_k<0, false><<<gemmGrid, blk, 0, stream>>>(
        esm, FIN, FIN, lin0_W, lin0_b, nullptr, x0, HDIM, NNODES);

    const float* xcur = x0;
    int ldx = HDIM;

    for (int i = 0; i < NLAYERS; ++i) {
        const size_t wo = (size_t)i * HDIM * HDIM;
        const size_t bo = (size_t)i * HDIM;

        // xm = x * mask (or x for layer 0)
        const float* xm; int ldxm;
        if (i == 0) { xm = xcur; ldxm = ldx; }
        else {
            elemmul_k<<<emGrid, blk, 0, stream>>>(xcur, ldx, maskb, bufA);
            xm = bufA; ldxm = HDIM;
        }
        // h_nb = xm @ W2 + b2
        gemm_k<0, false><<<gemmGrid, blk, 0, stream>>>(
            xm, ldxm, HDIM, wc_W2 + wo, wc_b2 + bo, nullptr, bufB, HDIM, NNODES);
        // agg = segment_sum(h_nb[src], dst)
        hipMemsetAsync(bufC, 0, NH * sizeof(float), stream);
        scatter_k<<<scGrid, blk, 0, stream>>>(bufB, src, dst, bufC);
        // h = relu(agg + xm @ W1 + b1)
        gemm_k<1, true><<<gemmGrid, blk, 0, stream>>>(
            xm, ldxm, HDIM, wc_W1 + wo, wc_b1 + bo, bufC, bufB, HDIM, NNODES);
        // mask = sigmoid(h @ W3 + b3)
        gemm_k<2, false><<<gemmGrid, blk, 0, stream>>>(
            bufB, HDIM, HDIM, wc_W3 + wo, wc_b3 + bo, nullptr, maskb, HDIM, NNODES);
        // xg = x * mask
        elemmul_k<<<emGrid, blk, 0, stream>>>(xcur, ldx, maskb, bufA);
        // agg2 = segment_sum(xg[src], dst)
        hipMemsetAsync(bufC, 0, NH * sizeof(float), stream);
        scatter_k<<<scGrid, blk, 0, stream>>>(bufA, src, dst, bufC);
        // tmp = agg2 @ Wn + bn
        gemm_k<0, false><<<gemmGrid, blk, 0, stream>>>(
            bufC, HDIM, HDIM, sc_Wn + wo, sc_bn + bo, nullptr, bufB, HDIM, NNODES);
        // x_new = relu(tmp + x @ Wr)  -> written directly into d_out slice i
        float* xn = out + (size_t)i * HDIM;
        gemm_k<1, true><<<gemmGrid, blk, 0, stream>>>(
            xcur, ldx, HDIM, sc_Wr + wo, nullptr, bufB, xn, LDOUT, NNODES);

        xcur = xn;
        ldx = LDOUT;
    }

    // node_mask: all true -> 1.0f
    const size_t maskOff = (size_t)NNODES * LDOUT;  // 100*500*1024
    fill1_k<<<(NNODES + 255) / 256, blk, 0, stream>>>(out + maskOff, NNODES);
}

// Round 2
// 3530.969 us; speedup vs baseline: 6.7523x; 6.7523x over previous
//
#include <hip/hip_runtime.h>

#define NNODES 50000
#define HDIM 256
#define NLAYERS 4
#define NEDGES 800000
#define FIN 1280
#define LDOUT 1024

// ---------------------------------------------------------------------------
// GEMM: C[n, 0:256] = act( A[n,:K] @ W[K,256] + bias + (HAS_D ? D[n,:] : 0) )
// ACT: 0 none, 1 relu, 2 sigmoid.
// ---------------------------------------------------------------------------
template<int ACT, bool HAS_D>
__global__ __launch_bounds__(256) void gemm_k(
    const float* __restrict__ A, int lda, int K,
    const float* __restrict__ W,
    const float* __restrict__ bias,
    const float* __restrict__ D,
    float* __restrict__ C, int ldc,
    int nrows)
{
    __shared__ float As[16][68];   // [k][row]
    __shared__ float Bs[16][68];   // [k][col]

    const int bx = blockIdx.x & 3;        // 4 col blocks (256/64)
    const int by = blockIdx.x >> 2;
    const int row0 = by * 64;
    const int col0 = bx * 64;
    const int tid = threadIdx.x;
    const int tx = tid & 15;
    const int ty = tid >> 4;

    float acc[4][4] = {};

    for (int k0 = 0; k0 < K; k0 += 16) {
        {
            const int r = tid >> 2;
            const int c = (tid & 3) * 4;
            const int grow = row0 + r;
            float4 v = make_float4(0.f, 0.f, 0.f, 0.f);
            if (grow < nrows)
                v = *(const float4*)(A + (size_t)grow * lda + k0 + c);
            As[c + 0][r] = v.x; As[c + 1][r] = v.y;
            As[c + 2][r] = v.z; As[c + 3][r] = v.w;
        }
        {
            const int r = tid >> 4;
            const int c = (tid & 15) * 4;
            float4 v = *(const float4*)(W + (size_t)(k0 + r) * HDIM + col0 + c);
            Bs[r][c + 0] = v.x; Bs[r][c + 1] = v.y;
            Bs[r][c + 2] = v.z; Bs[r][c + 3] = v.w;
        }
        __syncthreads();
        #pragma unroll
        for (int k = 0; k < 16; ++k) {
            float a[4], b[4];
            #pragma unroll
            for (int i = 0; i < 4; ++i) a[i] = As[k][ty * 4 + i];
            #pragma unroll
            for (int j = 0; j < 4; ++j) b[j] = Bs[k][tx * 4 + j];
            #pragma unroll
            for (int i = 0; i < 4; ++i)
                #pragma unroll
                for (int j = 0; j < 4; ++j)
                    acc[i][j] += a[i] * b[j];
        }
        __syncthreads();
    }

    #pragma unroll
    for (int i = 0; i < 4; ++i) {
        const int grow = row0 + ty * 4 + i;
        if (grow < nrows) {
            #pragma unroll
            for (int j = 0; j < 4; ++j) {
                const int gcol = col0 + tx * 4 + j;
                float v = acc[i][j];
                if (bias) v += bias[gcol];
                if (HAS_D) v += D[(size_t)grow * HDIM + gcol];
                if (ACT == 1) v = fmaxf(v, 0.f);
                if (ACT == 2) v = 1.f / (1.f + expf(-v));
                C[(size_t)grow * ldc + gcol] = v;
            }
        }
    }
}

// ---------------------------------------------------------------------------
// CSR build: histogram -> exclusive scan -> bucket-scatter of src ids
// ---------------------------------------------------------------------------
__global__ __launch_bounds__(256) void count_k(
    const int* __restrict__ dstIdx, int* __restrict__ counts)
{
    const int e = blockIdx.x * 256 + threadIdx.x;
    if (e < NEDGES) atomicAdd(&counts[dstIdx[e]], 1);
}

__global__ __launch_bounds__(1024) void scan_k(
    const int* __restrict__ counts, int* __restrict__ starts)
{
    __shared__ int sm[1024];
    __shared__ int s_off;
    if (threadIdx.x == 0) s_off = 0;
    __syncthreads();
    for (int base = 0; base < NNODES; base += 1024) {
        const int i = base + threadIdx.x;
        const int v = (i < NNODES) ? counts[i] : 0;
        sm[threadIdx.x] = v;
        __syncthreads();
        for (int ofs = 1; ofs < 1024; ofs <<= 1) {
            const int t = (threadIdx.x >= ofs) ? sm[threadIdx.x - ofs] : 0;
            __syncthreads();
            sm[threadIdx.x] += t;
            __syncthreads();
        }
        const int incl = sm[threadIdx.x];
        const int off = s_off;
        if (i < NNODES) starts[i] = off + incl - v;   // exclusive prefix
        __syncthreads();
        if (threadIdx.x == 1023) s_off = off + incl;
        __syncthreads();
    }
    if (threadIdx.x == 0) starts[NNODES] = s_off;
}

__global__ __launch_bounds__(256) void fillcsr_k(
    const int* __restrict__ srcIdx, const int* __restrict__ dstIdx,
    int* __restrict__ cursor, int* __restrict__ csr)
{
    const int e = blockIdx.x * 256 + threadIdx.x;
    if (e >= NEDGES) return;
    const int d = dstIdx[e];
    const int p = atomicAdd(&cursor[d], 1);
    csr[p] = srcIdx[e];
}

// ---------------------------------------------------------------------------
// gather-sum: out[n,:] = sum_{e in csr bucket n} rows[csr[e], :]
// one wave (64 lanes, float4/lane) per node
// ---------------------------------------------------------------------------
__global__ __launch_bounds__(256) void gather_sum_k(
    const float* __restrict__ rows, int ldr,
    const int* __restrict__ csr,
    const int* __restrict__ starts,
    float* __restrict__ out)
{
    const int node = (blockIdx.x * 256 + threadIdx.x) >> 6;
    const int lane = threadIdx.x & 63;
    if (node >= NNODES) return;
    const int e0 = starts[node];
    const int e1 = starts[node + 1];
    float4 acc = make_float4(0.f, 0.f, 0.f, 0.f);
    for (int e = e0; e < e1; ++e) {
        const int s = csr[e];
        const float4 v = *(const float4*)(rows + (size_t)s * ldr + lane * 4);
        acc.x += v.x; acc.y += v.y; acc.z += v.z; acc.w += v.w;
    }
    *(float4*)(out + (size_t)node * HDIM + lane * 4) = acc;
}

// ---------------------------------------------------------------------------
__global__ __launch_bounds__(256) void elemmul_k(
    const float* __restrict__ x, int ldx,
    const float* __restrict__ m,
    float* __restrict__ o)
{
    const int t = blockIdx.x * 256 + threadIdx.x;
    const int total = NNODES * (HDIM / 4);
    if (t >= total) return;
    const int row = t / (HDIM / 4);
    const int c = (t % (HDIM / 4)) * 4;
    const float4 xv = *(const float4*)(x + (size_t)row * ldx + c);
    const float4 mv = *(const float4*)(m + (size_t)row * HDIM + c);
    float4 r;
    r.x = xv.x * mv.x; r.y = xv.y * mv.y;
    r.z = xv.z * mv.z; r.w = xv.w * mv.w;
    *(float4*)(o + (size_t)row * HDIM + c) = r;
}

__global__ __launch_bounds__(256) void fill1_k(float* __restrict__ p, int n)
{
    const int t = blockIdx.x * 256 + threadIdx.x;
    if (t < n) p[t] = 1.0f;
}

// ---------------------------------------------------------------------------
extern "C" void kernel_launch(void* const* d_in, const int* in_sizes, int n_in,
                              void* d_out, int out_size, void* d_ws, size_t ws_size,
                              hipStream_t stream)
{
    const int*   edge   = (const int*)d_in[1];
    const int*   src    = edge;
    const int*   dst    = edge + NEDGES;
    const float* esm    = (const float*)d_in[2];
    const float* lin0_W = (const float*)d_in[4];
    const float* lin0_b = (const float*)d_in[5];
    const float* wc_W1  = (const float*)d_in[6];
    const float* wc_b1  = (const float*)d_in[7];
    const float* wc_W2  = (const float*)d_in[8];
    const float* wc_b2  = (const float*)d_in[9];
    const float* wc_W3  = (const float*)d_in[10];
    const float* wc_b3  = (const float*)d_in[11];
    const float* sc_Wn  = (const float*)d_in[12];
    const float* sc_bn  = (const float*)d_in[13];
    const float* sc_Wr  = (const float*)d_in[14];
    float* out = (float*)d_out;

    const size_t NH = (size_t)NNODES * HDIM;
    float* ws    = (float*)d_ws;
    float* x0    = ws;            // x after lin0
    float* maskb = ws + NH;       // mask_val
    float* bufA  = ws + 2 * NH;   // xm / xg
    float* bufB  = ws + 3 * NH;   // h_nb / h / tmp
    float* bufC  = ws + 4 * NH;   // agg
    int*   iws    = (int*)(ws + 5 * NH);
    int*   counts = iws;                    // [NNODES]
    int*   starts = iws + NNODES;           // [NNODES+1]
    int*   cursor = iws + 2 * NNODES + 1;   // [NNODES]
    int*   csr    = iws + 3 * NNODES + 2;   // [NEDGES]

    const dim3 blk(256);
    const int rowBlocks = (NNODES + 63) / 64;
    const dim3 gemmGrid(rowBlocks * 4);
    const int emGrid = (NNODES * (HDIM / 4) + 255) / 256;
    const int edgeGrid = (NEDGES + 255) / 256;
    const int gsGrid = (NNODES * 64 + 255) / 256;   // one wave per node

    // ---- build CSR (dst-bucketed src lists), reused by all 8 aggregations
    hipMemsetAsync(counts, 0, NNODES * sizeof(int), stream);
    count_k<<<edgeGrid, blk, 0, stream>>>(dst, counts);
    scan_k<<<1, 1024, 0, stream>>>(counts, starts);
    hipMemcpyAsync(cursor, starts, NNODES * sizeof(int),
                   hipMemcpyDeviceToDevice, stream);
    fillcsr_k<<<edgeGrid, blk, 0, stream>>>(src, dst, cursor, csr);

    // x = esm @ lin0_W + lin0_b
    gemm_k<0, false><<<gemmGrid, blk, 0, stream>>>(
        esm, FIN, FIN, lin0_W, lin0_b, nullptr, x0, HDIM, NNODES);

    const float* xcur = x0;
    int ldx = HDIM;

    for (int i = 0; i < NLAYERS; ++i) {
        const size_t wo = (size_t)i * HDIM * HDIM;
        const size_t bo = (size_t)i * HDIM;

        // xm = x * mask (or x for layer 0)
        const float* xm; int ldxm;
        if (i == 0) { xm = xcur; ldxm = ldx; }
        else {
            elemmul_k<<<emGrid, blk, 0, stream>>>(xcur, ldx, maskb, bufA);
            xm = bufA; ldxm = HDIM;
        }
        // h_nb = xm @ W2 + b2
        gemm_k<0, false><<<gemmGrid, blk, 0, stream>>>(
            xm, ldxm, HDIM, wc_W2 + wo, wc_b2 + bo, nullptr, bufB, HDIM, NNODES);
        // agg = segment_sum(h_nb[src], dst)
        gather_sum_k<<<gsGrid, blk, 0, stream>>>(bufB, HDIM, csr, starts, bufC);
        // h = relu(agg + xm @ W1 + b1)
        gemm_k<1, true><<<gemmGrid, blk, 0, stream>>>(
            xm, ldxm, HDIM, wc_W1 + wo, wc_b1 + bo, bufC, bufB, HDIM, NNODES);
        // mask = sigmoid(h @ W3 + b3)
        gemm_k<2, false><<<gemmGrid, blk, 0, stream>>>(
            bufB, HDIM, HDIM, wc_W3 + wo, wc_b3 + bo, nullptr, maskb, HDIM, NNODES);
        // xg = x * mask
        elemmul_k<<<emGrid, blk, 0, stream>>>(xcur, ldx, maskb, bufA);
        // agg2 = segment_sum(xg[src], dst)
        gather_sum_k<<<gsGrid, blk, 0, stream>>>(bufA, HDIM, csr, starts, bufC);
        // tmp = agg2 @ Wn + bn
        gemm_k<0, false><<<gemmGrid, blk, 0, stream>>>(
            bufC, HDIM, HDIM, sc_Wn + wo, sc_bn + bo, nullptr, bufB, HDIM, NNODES);
        // x_new = relu(tmp + x @ Wr)  -> written directly into d_out slice i
        float* xn = out + (size_t)i * HDIM;
        gemm_k<1, true><<<gemmGrid, blk, 0, stream>>>(
            xcur, ldx, HDIM, sc_Wr + wo, nullptr, bufB, xn, LDOUT, NNODES);

        xcur = xn;
        ldx = LDOUT;
    }

    // node_mask: all true -> 1.0f
    const size_t maskOff = (size_t)NNODES * LDOUT;
    fill1_k<<<(NNODES + 255) / 256, blk, 0, stream>>>(out + maskOff, NNODES);
}

// Round 3
// 1867.139 us; speedup vs baseline: 12.7694x; 1.8911x over previous
//
#include <hip/hip_runtime.h>

#define NNODES 50000
#define HDIM 256
#define NLAYERS 4
#define NEDGES 800000
#define FIN 1280
#define LDOUT 1024

typedef _Float16 f16;
typedef __attribute__((ext_vector_type(8))) _Float16 f16x8;
typedef __attribute__((ext_vector_type(4))) _Float16 f16x4;
typedef __attribute__((ext_vector_type(4))) float f32x4;

enum { SRC_F32 = 0, SRC_MUL = 1, SRC_ADDRELU = 2, SRC_CONCAT = 3 };
enum { EPI_F32 = 0, EPI_F16B = 1 };
enum { ACT_NONE = 0, ACT_RELU = 1, ACT_SIG = 2 };

// ---------------------------------------------------------------------------
// MFMA GEMM: C[row, 0:256] = act( stage(A)[row,:K] @ W[K,256] + bias )
// A staged to f16 with fused elementwise op; W pre-packed col-major f16
// (Wt[col][k]).  Block: 256 thr = 4 waves; tile BM=64 x BN=256, BK=64.
// Wave w covers cols [w*64, w*64+64).  LDS is fragment-major (lane-linear
// ds_read_b128, conflict-free).
// Verified MFMA layouts (learn_hip m89/m92): A row=lane&15,k=(lane>>4)*8+j;
// B col=lane&15 (from col-major Wt); C/D col=lane&15,row=(lane>>4)*4+reg.
// ---------------------------------------------------------------------------
template<int SRC, int EPI, int ACT, int KTILES>
__global__ __launch_bounds__(256) void mgemm_k(
    const float* __restrict__ A1, int lda1,      // x / esm / agg
    const float* __restrict__ A2,                // mask (MUL) / xw1 (ADDRELU)
    const f16*  __restrict__ A3,                 // agg2 f16 (CONCAT)
    const float* __restrict__ sbias,             // b1 (ADDRELU, indexed by k)
    const f16*  __restrict__ Wt,                 // [256][K] col-major f16
    const float* __restrict__ bias,              // epilogue bias (may be null)
    float* __restrict__ Cf, int ldc,             // f32 out
    f16*  __restrict__ Ch)                       // f16 out (ld 256)
{
    constexpr int K = KTILES * 64;
    __shared__ f16 Asm[4096];                    // 8 KB fragment-major

    const int row0 = blockIdx.x * 64;
    const int tid = threadIdx.x;
    const int wv = tid >> 6;
    const int l = tid & 63;

    f32x4 acc[4][4] = {};

    // staging: thread t loads row sr, k-cols [sc0, sc0+16)
    const int sr  = tid >> 2;
    const int sc0 = (tid & 3) * 16;
    const int grow = row0 + sr;
    const bool rok = grow < NNODES;
    // LDS dest for the two 8-element chunks (fragment-major):
    //   region (kb*4+rf), lane_i = (sr&15) + ch*16, 8 f16 per lane slot
    const int rf_s = sr >> 4;
    const int lane_base0 =
        (((sc0 >> 5) * 4 + rf_s) * 64 + (sr & 15) + (((sc0 & 31) >> 3) * 16)) * 8;
    const int lane_base1 = lane_base0 + 16 * 8;  // next chunk (ch+1)

    for (int kt = 0; kt < KTILES; ++kt) {
        const int k0 = kt * 64;
        f16x8 av0, av1;
        #pragma unroll
        for (int i = 0; i < 8; ++i) { av0[i] = (f16)0.f; av1[i] = (f16)0.f; }
        if (rok) {
            if (SRC == SRC_CONCAT && k0 < HDIM) {
                av0 = *(const f16x8*)(A3 + (size_t)grow * HDIM + k0 + sc0);
                av1 = *(const f16x8*)(A3 + (size_t)grow * HDIM + k0 + sc0 + 8);
            } else {
                const int kk = (SRC == SRC_CONCAT) ? (k0 - HDIM) : k0;
                #pragma unroll
                for (int h = 0; h < 4; ++h) {
                    float4 v = *(const float4*)(A1 + (size_t)grow * lda1 + kk + sc0 + h * 4);
                    float r0 = v.x, r1 = v.y, r2 = v.z, r3 = v.w;
                    if (SRC == SRC_MUL) {
                        float4 m = *(const float4*)(A2 + (size_t)grow * HDIM + k0 + sc0 + h * 4);
                        r0 *= m.x; r1 *= m.y; r2 *= m.z; r3 *= m.w;
                    }
                    if (SRC == SRC_ADDRELU) {
                        float4 w = *(const float4*)(A2 + (size_t)grow * HDIM + k0 + sc0 + h * 4);
                        float4 b = *(const float4*)(sbias + k0 + sc0 + h * 4);
                        r0 = fmaxf(r0 + w.x + b.x, 0.f);
                        r1 = fmaxf(r1 + w.y + b.y, 0.f);
                        r2 = fmaxf(r2 + w.z + b.z, 0.f);
                        r3 = fmaxf(r3 + w.w + b.w, 0.f);
                    }
                    if (h < 2) {
                        av0[h * 4 + 0] = (f16)r0; av0[h * 4 + 1] = (f16)r1;
                        av0[h * 4 + 2] = (f16)r2; av0[h * 4 + 3] = (f16)r3;
                    } else {
                        av1[(h - 2) * 4 + 0] = (f16)r0; av1[(h - 2) * 4 + 1] = (f16)r1;
                        av1[(h - 2) * 4 + 2] = (f16)r2; av1[(h - 2) * 4 + 3] = (f16)r3;
                    }
                }
            }
        }
        *(f16x8*)(Asm + lane_base0) = av0;
        *(f16x8*)(Asm + lane_base1) = av1;
        __syncthreads();

        f16x8 af[4][2];
        #pragma unroll
        for (int rf = 0; rf < 4; ++rf)
            #pragma unroll
            for (int kb = 0; kb < 2; ++kb)
                af[rf][kb] = *(const f16x8*)(Asm + ((kb * 4 + rf) * 64 + l) * 8);
        f16x8 bfr[4][2];
        #pragma unroll
        for (int cf = 0; cf < 4; ++cf) {
            const int col = wv * 64 + cf * 16 + (l & 15);
            const f16* bp = Wt + (size_t)col * K + k0 + ((l >> 4) * 8);
            bfr[cf][0] = *(const f16x8*)(bp);
            bfr[cf][1] = *(const f16x8*)(bp + 32);
        }
        #pragma unroll
        for (int cf = 0; cf < 4; ++cf)
            #pragma unroll
            for (int rf = 0; rf < 4; ++rf)
                #pragma unroll
                for (int kb = 0; kb < 2; ++kb)
                    acc[rf][cf] = __builtin_amdgcn_mfma_f32_16x16x32_f16(
                        af[rf][kb], bfr[cf][kb], acc[rf][cf], 0, 0, 0);
        __syncthreads();
    }

    #pragma unroll
    for (int rf = 0; rf < 4; ++rf) {
        #pragma unroll
        for (int j = 0; j < 4; ++j) {
            const int row = row0 + rf * 16 + ((l >> 4) * 4) + j;
            if (row >= NNODES) continue;
            #pragma unroll
            for (int cf = 0; cf < 4; ++cf) {
                const int col = wv * 64 + cf * 16 + (l & 15);
                float v = acc[rf][cf][j];
                if (bias) v += bias[col];
                if (ACT == ACT_RELU) v = fmaxf(v, 0.f);
                if (ACT == ACT_SIG)  v = 1.f / (1.f + expf(-v));
                if (EPI == EPI_F32) Cf[(size_t)row * ldc + col] = v;
                else                Ch[(size_t)row * HDIM + col] = (f16)v;
            }
        }
    }
}

// ---------------------------------------------------------------------------
// weight pre-pack: Wt[col][k] f16  <-  W[k][col] f32    (N=256 cols)
// ---------------------------------------------------------------------------
__global__ __launch_bounds__(256) void pack_t_k(
    const float* __restrict__ W, f16* __restrict__ Wt, int K)
{
    const int idx = blockIdx.x * 256 + threadIdx.x;
    if (idx >= 256 * K) return;
    const int col = idx / K, k = idx % K;
    Wt[idx] = (f16)W[k * 256 + col];
}

// WtC[col][k] (K=512): k<256 -> Wn[k][col], k>=256 -> Wr[k-256][col]
__global__ __launch_bounds__(256) void pack_cat_k(
    const float* __restrict__ Wn, const float* __restrict__ Wr,
    f16* __restrict__ Wt)
{
    const int idx = blockIdx.x * 256 + threadIdx.x;
    if (idx >= 256 * 512) return;
    const int col = idx / 512, k = idx % 512;
    Wt[idx] = (f16)(k < 256 ? Wn[k * 256 + col] : Wr[(k - 256) * 256 + col]);
}

// ---------------------------------------------------------------------------
// CSR build (reused from R2)
// ---------------------------------------------------------------------------
__global__ __launch_bounds__(256) void count_k(
    const int* __restrict__ dstIdx, int* __restrict__ counts)
{
    const int e = blockIdx.x * 256 + threadIdx.x;
    if (e < NEDGES) atomicAdd(&counts[dstIdx[e]], 1);
}

__global__ __launch_bounds__(1024) void scan_k(
    const int* __restrict__ counts, int* __restrict__ starts)
{
    __shared__ int sm[1024];
    __shared__ int s_off;
    if (threadIdx.x == 0) s_off = 0;
    __syncthreads();
    for (int base = 0; base < NNODES; base += 1024) {
        const int i = base + threadIdx.x;
        const int v = (i < NNODES) ? counts[i] : 0;
        sm[threadIdx.x] = v;
        __syncthreads();
        for (int ofs = 1; ofs < 1024; ofs <<= 1) {
            const int t = (threadIdx.x >= ofs) ? sm[threadIdx.x - ofs] : 0;
            __syncthreads();
            sm[threadIdx.x] += t;
            __syncthreads();
        }
        const int incl = sm[threadIdx.x];
        const int off = s_off;
        if (i < NNODES) starts[i] = off + incl - v;
        __syncthreads();
        if (threadIdx.x == 1023) s_off = off + incl;
        __syncthreads();
    }
    if (threadIdx.x == 0) starts[NNODES] = s_off;
}

__global__ __launch_bounds__(256) void fillcsr_k(
    const int* __restrict__ srcIdx, const int* __restrict__ dstIdx,
    int* __restrict__ cursor, int* __restrict__ csr)
{
    const int e = blockIdx.x * 256 + threadIdx.x;
    if (e >= NEDGES) return;
    const int d = dstIdx[e];
    const int p = atomicAdd(&cursor[d], 1);
    csr[p] = srcIdx[e];
}

// ---------------------------------------------------------------------------
// gather-sums: one wave per node, f16 rows in, f32 accum
// ---------------------------------------------------------------------------
__global__ __launch_bounds__(256) void gather_h_k(   // f16 -> f32
    const f16* __restrict__ rows, const int* __restrict__ csr,
    const int* __restrict__ starts, float* __restrict__ out)
{
    const int node = (blockIdx.x * 256 + threadIdx.x) >> 6;
    const int lane = threadIdx.x & 63;
    if (node >= NNODES) return;
    const int e0 = starts[node], e1 = starts[node + 1];
    float a0 = 0, a1 = 0, a2 = 0, a3 = 0, b0 = 0, b1 = 0, b2 = 0, b3 = 0;
    int e = e0;
    for (; e + 1 < e1; e += 2) {
        const int s0 = csr[e], s1 = csr[e + 1];
        f16x4 v0 = *(const f16x4*)(rows + (size_t)s0 * HDIM + lane * 4);
        f16x4 v1 = *(const f16x4*)(rows + (size_t)s1 * HDIM + lane * 4);
        a0 += (float)v0[0]; a1 += (float)v0[1]; a2 += (float)v0[2]; a3 += (float)v0[3];
        b0 += (float)v1[0]; b1 += (float)v1[1]; b2 += (float)v1[2]; b3 += (float)v1[3];
    }
    if (e < e1) {
        const int s0 = csr[e];
        f16x4 v0 = *(const f16x4*)(rows + (size_t)s0 * HDIM + lane * 4);
        a0 += (float)v0[0]; a1 += (float)v0[1]; a2 += (float)v0[2]; a3 += (float)v0[3];
    }
    *(float4*)(out + (size_t)node * HDIM + lane * 4) =
        make_float4(a0 + b0, a1 + b1, a2 + b2, a3 + b3);
}

__global__ __launch_bounds__(256) void gather_g_k(   // f16 -> f16
    const f16* __restrict__ rows, const int* __restrict__ csr,
    const int* __restrict__ starts, f16* __restrict__ out)
{
    const int node = (blockIdx.x * 256 + threadIdx.x) >> 6;
    const int lane = threadIdx.x & 63;
    if (node >= NNODES) return;
    const int e0 = starts[node], e1 = starts[node + 1];
    float a0 = 0, a1 = 0, a2 = 0, a3 = 0, b0 = 0, b1 = 0, b2 = 0, b3 = 0;
    int e = e0;
    for (; e + 1 < e1; e += 2) {
        const int s0 = csr[e], s1 = csr[e + 1];
        f16x4 v0 = *(const f16x4*)(rows + (size_t)s0 * HDIM + lane * 4);
        f16x4 v1 = *(const f16x4*)(rows + (size_t)s1 * HDIM + lane * 4);
        a0 += (float)v0[0]; a1 += (float)v0[1]; a2 += (float)v0[2]; a3 += (float)v0[3];
        b0 += (float)v1[0]; b1 += (float)v1[1]; b2 += (float)v1[2]; b3 += (float)v1[3];
    }
    if (e < e1) {
        const int s0 = csr[e];
        f16x4 v0 = *(const f16x4*)(rows + (size_t)s0 * HDIM + lane * 4);
        a0 += (float)v0[0]; a1 += (float)v0[1]; a2 += (float)v0[2]; a3 += (float)v0[3];
    }
    f16x4 r;
    r[0] = (f16)(a0 + b0); r[1] = (f16)(a1 + b1);
    r[2] = (f16)(a2 + b2); r[3] = (f16)(a3 + b3);
    *(f16x4*)(out + (size_t)node * HDIM + lane * 4) = r;
}

// ---------------------------------------------------------------------------
// xg = x * mask -> f16   (one wave per row, 4 cols/lane)
// ---------------------------------------------------------------------------
__global__ __launch_bounds__(256) void elemmul_xg_k(
    const float* __restrict__ x, int ldx,
    const float* __restrict__ m, f16* __restrict__ o)
{
    const int t = blockIdx.x * 256 + threadIdx.x;
    const int row = t >> 6;
    const int c = (t & 63) * 4;
    if (row >= NNODES) return;
    const float4 xv = *(const float4*)(x + (size_t)row * ldx + c);
    const float4 mv = *(const float4*)(m + (size_t)row * HDIM + c);
    f16x4 r;
    r[0] = (f16)(xv.x * mv.x); r[1] = (f16)(xv.y * mv.y);
    r[2] = (f16)(xv.z * mv.z); r[3] = (f16)(xv.w * mv.w);
    *(f16x4*)(o + (size_t)row * HDIM + c) = r;
}

__global__ __launch_bounds__(256) void fill1_k(float* __restrict__ p, int n)
{
    const int t = blockIdx.x * 256 + threadIdx.x;
    if (t < n) p[t] = 1.0f;
}

// ---------------------------------------------------------------------------
extern "C" void kernel_launch(void* const* d_in, const int* in_sizes, int n_in,
                              void* d_out, int out_size, void* d_ws, size_t ws_size,
                              hipStream_t stream)
{
    const int*   edge   = (const int*)d_in[1];
    const int*   src    = edge;
    const int*   dst    = edge + NEDGES;
    const float* esm    = (const float*)d_in[2];
    const float* lin0_W = (const float*)d_in[4];
    const float* lin0_b = (const float*)d_in[5];
    const float* wc_W1  = (const float*)d_in[6];
    const float* wc_b1  = (const float*)d_in[7];
    const float* wc_W2  = (const float*)d_in[8];
    const float* wc_b2  = (const float*)d_in[9];
    const float* wc_W3  = (const float*)d_in[10];
    const float* wc_b3  = (const float*)d_in[11];
    const float* sc_Wn  = (const float*)d_in[12];
    const float* sc_bn  = (const float*)d_in[13];
    const float* sc_Wr  = (const float*)d_in[14];
    float* out = (float*)d_out;

    const size_t NH = (size_t)NNODES * HDIM;
    float* ws    = (float*)d_ws;
    float* x0    = ws;                    // f32 [N,256]
    float* maskb = ws + NH;               // f32 [N,256]
    float* xw1   = ws + 2 * NH;           // f32 [N,256]
    float* aggf  = ws + 3 * NH;           // f32 [N,256]
    f16*   hnb   = (f16*)(ws + 4 * NH);   // f16 [N,256]  (also reused as xg)
    f16*   agg2  = hnb + NH;              // f16 [N,256]
    f16*   wbase = (f16*)(ws + 5 * NH);
    f16*   lin0t = wbase;                 // 256*1280
    f16*   W2t   = lin0t + 256 * FIN;     // 4 * 65536
    f16*   W1t   = W2t + 4 * 65536;
    f16*   W3t   = W1t + 4 * 65536;
    f16*   WtC   = W3t + 4 * 65536;       // 4 * 131072
    int*   iws    = (int*)(WtC + 4 * 131072);
    int*   counts = iws;
    int*   starts = iws + NNODES;
    int*   cursor = iws + 2 * NNODES + 1;
    int*   csr    = iws + 3 * NNODES + 2;

    const dim3 blk(256);
    const int gemmGrid = (NNODES + 63) / 64;           // 782
    const int edgeGrid = (NEDGES + 255) / 256;
    const int waveGrid = (NNODES * 64) / 256;          // 12500

    // ---- CSR build (dst-bucketed src lists)
    hipMemsetAsync(counts, 0, NNODES * sizeof(int), stream);
    count_k<<<edgeGrid, blk, 0, stream>>>(dst, counts);
    scan_k<<<1, 1024, 0, stream>>>(counts, starts);
    hipMemcpyAsync(cursor, starts, NNODES * sizeof(int),
                   hipMemcpyDeviceToDevice, stream);
    fillcsr_k<<<edgeGrid, blk, 0, stream>>>(src, dst, cursor, csr);

    // ---- weight pre-pack (f16, col-major)
    pack_t_k<<<(256 * FIN + 255) / 256, blk, 0, stream>>>(lin0_W, lin0t, FIN);
    for (int i = 0; i < NLAYERS; ++i) {
        const size_t wo = (size_t)i * HDIM * HDIM;
        pack_t_k<<<(256 * 256 + 255) / 256, blk, 0, stream>>>(wc_W2 + wo, W2t + i * 65536, 256);
        pack_t_k<<<(256 * 256 + 255) / 256, blk, 0, stream>>>(wc_W1 + wo, W1t + i * 65536, 256);
        pack_t_k<<<(256 * 256 + 255) / 256, blk, 0, stream>>>(wc_W3 + wo, W3t + i * 65536, 256);
        pack_cat_k<<<(256 * 512 + 255) / 256, blk, 0, stream>>>(sc_Wn + wo, sc_Wr + wo, WtC + i * 131072);
    }

    // ---- lin0: x0 = esm @ W + b
    mgemm_k<SRC_F32, EPI_F32, ACT_NONE, FIN / 64><<<gemmGrid, blk, 0, stream>>>(
        esm, FIN, nullptr, nullptr, nullptr, lin0t, lin0_b, x0, HDIM, nullptr);

    const float* xcur = x0;
    int ldx = HDIM;

    for (int i = 0; i < NLAYERS; ++i) {
        const size_t bo = (size_t)i * HDIM;
        const f16* w2 = W2t + i * 65536;
        const f16* w1 = W1t + i * 65536;
        const f16* w3 = W3t + i * 65536;
        const f16* wc = WtC + i * 131072;

        // h_nb = xm@W2 + b2 (f16), xw1 = xm@W1 (f32); xm fused in staging
        if (i == 0) {
            mgemm_k<SRC_F32, EPI_F16B, ACT_NONE, 4><<<gemmGrid, blk, 0, stream>>>(
                xcur, ldx, nullptr, nullptr, nullptr, w2, wc_b2 + bo, nullptr, 0, hnb);
            mgemm_k<SRC_F32, EPI_F32, ACT_NONE, 4><<<gemmGrid, blk, 0, stream>>>(
                xcur, ldx, nullptr, nullptr, nullptr, w1, nullptr, xw1, HDIM, nullptr);
        } else {
            mgemm_k<SRC_MUL, EPI_F16B, ACT_NONE, 4><<<gemmGrid, blk, 0, stream>>>(
                xcur, ldx, maskb, nullptr, nullptr, w2, wc_b2 + bo, nullptr, 0, hnb);
            mgemm_k<SRC_MUL, EPI_F32, ACT_NONE, 4><<<gemmGrid, blk, 0, stream>>>(
                xcur, ldx, maskb, nullptr, nullptr, w1, nullptr, xw1, HDIM, nullptr);
        }
        // agg = segment_sum(h_nb[src], dst)
        gather_h_k<<<waveGrid, blk, 0, stream>>>(hnb, csr, starts, aggf);
        // mask = sigmoid( relu(agg + xw1 + b1) @ W3 + b3 )
        mgemm_k<SRC_ADDRELU, EPI_F32, ACT_SIG, 4><<<gemmGrid, blk, 0, stream>>>(
            aggf, HDIM, xw1, nullptr, wc_b1 + bo, w3, wc_b3 + bo, maskb, HDIM, nullptr);
        // xg = x * mask (f16, reuses hnb buffer)
        elemmul_xg_k<<<waveGrid, blk, 0, stream>>>(xcur, ldx, maskb, hnb);
        // agg2 = segment_sum(xg[src], dst)  (f16)
        gather_g_k<<<waveGrid, blk, 0, stream>>>(hnb, csr, starts, agg2);
        // x_new = relu([agg2 | x] @ [Wn;Wr] + bn) -> d_out slice i
        float* xn = out + (size_t)i * HDIM;
        mgemm_k<SRC_CONCAT, EPI_F32, ACT_RELU, 8><<<gemmGrid, blk, 0, stream>>>(
            xcur, ldx, nullptr, agg2, nullptr, wc, sc_bn + bo, xn, LDOUT, nullptr);

        xcur = xn;
        ldx = LDOUT;
    }

    // node_mask: all true
    const size_t maskOff = (size_t)NNODES * LDOUT;
    fill1_k<<<(NNODES + 255) / 256, blk, 0, stream>>>(out + maskOff, NNODES);
}

// Round 4
// 1691.134 us; speedup vs baseline: 14.0984x; 1.1041x over previous
//
#include <hip/hip_runtime.h>

#define NNODES 50000
#define HDIM 256
#define NLAYERS 4
#define NEDGES 800000
#define FIN 1280
#define LDOUT 1024

typedef _Float16 f16;
typedef __attribute__((ext_vector_type(8))) _Float16 f16x8;
typedef __attribute__((ext_vector_type(4))) _Float16 f16x4;
typedef __attribute__((ext_vector_type(4))) float f32x4;

enum { SRC_F32 = 0, SRC_H = 1, SRC_MULH = 2, SRC_ADDRELU = 3, SRC_CATH = 4 };
enum { EPI_F32 = 0, EPI_F16 = 1, EPI_BOTH = 2 };
enum { ACT_NONE = 0, ACT_RELU = 1, ACT_SIG = 2 };

// ---------------------------------------------------------------------------
// Pipelined MFMA GEMM: C[row,0:256] = act( stage(A)[row,:K] @ Wt^T + bias )
// 256 thr = 4 waves; tile BM=64 x BN=256, BK=64; double-buffered LDS A-tile;
// per-iter: issue loads(t+1) -> barrier -> ds_read+Bload+MFMA -> commit(t+1).
// Staging variants (A side, fused elementwise):
//   SRC_F32: f32 A1 (lda1)           SRC_H: f16 A3
//   SRC_MULH: f16 A3 * f32 A2        SRC_ADDRELU: relu(A1 + A2 + sbias[k])
//   SRC_CATH: k<256 ? A3 : A4 (both f16)
// MFMA layouts as validated in R3 (passed refcheck): A row=l&15,k=(l>>4)*8+j;
// B col=l&15 (col-major Wt); C/D col=l&15, row=(l>>4)*4+reg.
// ---------------------------------------------------------------------------
template<int SRC, int EPI, int ACT, int KTILES>
__global__ __launch_bounds__(256) void mgemm_k(
    const float* __restrict__ A1, int lda1,
    const float* __restrict__ A2,
    const float* __restrict__ sbias,
    const f16*  __restrict__ A3,
    const f16*  __restrict__ A4,
    const f16*  __restrict__ Wt,       // [256][K] col-major f16
    const float* __restrict__ bias,
    float* __restrict__ Cf, int ldc,
    f16*  __restrict__ Ch)
{
    constexpr int K = KTILES * 64;
    __shared__ f16 Asm[2][4096];       // 2 x 8 KB

    const int row0 = blockIdx.x * 64;
    const int tid = threadIdx.x;
    const int wv = tid >> 6;
    const int l = tid & 63;

    f32x4 acc[4][4] = {};

    const int sr = tid >> 2;
    const int sc0 = (tid & 3) * 16;
    const int grow = row0 + sr;
    const bool rok = grow < NNODES;
    const int lane_base0 =
        (((sc0 >> 5) * 4 + (sr >> 4)) * 64 + (sr & 15) + (((sc0 & 31) >> 3) * 16)) * 8;
    const int lane_base1 = lane_base0 + 128;

    // B fragment base pointers (per cf, constant over kt)
    const f16* bp[4];
    #pragma unroll
    for (int cf = 0; cf < 4; ++cf)
        bp[cf] = Wt + (size_t)(wv * 64 + cf * 16 + (l & 15)) * K + ((l >> 4) * 8);

    // raw staging registers (constexpr-selected per SRC; unused eliminated)
    float4 rA0, rA1, rA2, rA3;
    float4 rB0, rB1, rB2, rB3;
    float4 rb0, rb1, rb2, rb3;
    f16x8 h0, h1;

    auto LOADS = [&](int kt) {
        if (!rok) return;
        const int k0 = kt * 64;
        if constexpr (SRC == SRC_F32) {
            const float* p = A1 + (size_t)grow * lda1 + k0 + sc0;
            rA0 = *(const float4*)(p + 0);  rA1 = *(const float4*)(p + 4);
            rA2 = *(const float4*)(p + 8);  rA3 = *(const float4*)(p + 12);
        } else if constexpr (SRC == SRC_H) {
            const f16* p = A3 + (size_t)grow * HDIM + k0 + sc0;
            h0 = *(const f16x8*)p;  h1 = *(const f16x8*)(p + 8);
        } else if constexpr (SRC == SRC_MULH) {
            const f16* p = A3 + (size_t)grow * HDIM + k0 + sc0;
            h0 = *(const f16x8*)p;  h1 = *(const f16x8*)(p + 8);
            const float* m = A2 + (size_t)grow * HDIM + k0 + sc0;
            rA0 = *(const float4*)(m + 0);  rA1 = *(const float4*)(m + 4);
            rA2 = *(const float4*)(m + 8);  rA3 = *(const float4*)(m + 12);
        } else if constexpr (SRC == SRC_ADDRELU) {
            const float* pa = A1 + (size_t)grow * HDIM + k0 + sc0;
            const float* pb = A2 + (size_t)grow * HDIM + k0 + sc0;
            const float* pc = sbias + k0 + sc0;
            rA0 = *(const float4*)(pa + 0);  rA1 = *(const float4*)(pa + 4);
            rA2 = *(const float4*)(pa + 8);  rA3 = *(const float4*)(pa + 12);
            rB0 = *(const float4*)(pb + 0);  rB1 = *(const float4*)(pb + 4);
            rB2 = *(const float4*)(pb + 8);  rB3 = *(const float4*)(pb + 12);
            rb0 = *(const float4*)(pc + 0);  rb1 = *(const float4*)(pc + 4);
            rb2 = *(const float4*)(pc + 8);  rb3 = *(const float4*)(pc + 12);
        } else { // SRC_CATH
            const f16* p = (k0 < HDIM)
                ? (A3 + (size_t)grow * HDIM + k0 + sc0)
                : (A4 + (size_t)grow * HDIM + (k0 - HDIM) + sc0);
            h0 = *(const f16x8*)p;  h1 = *(const f16x8*)(p + 8);
        }
    };

    auto COMMIT = [&](int b) {
        f16x8 av0, av1;
        #pragma unroll
        for (int i = 0; i < 8; ++i) { av0[i] = (f16)0.f; av1[i] = (f16)0.f; }
        if (rok) {
            if constexpr (SRC == SRC_F32) {
                av0[0]=(f16)rA0.x; av0[1]=(f16)rA0.y; av0[2]=(f16)rA0.z; av0[3]=(f16)rA0.w;
                av0[4]=(f16)rA1.x; av0[5]=(f16)rA1.y; av0[6]=(f16)rA1.z; av0[7]=(f16)rA1.w;
                av1[0]=(f16)rA2.x; av1[1]=(f16)rA2.y; av1[2]=(f16)rA2.z; av1[3]=(f16)rA2.w;
                av1[4]=(f16)rA3.x; av1[5]=(f16)rA3.y; av1[6]=(f16)rA3.z; av1[7]=(f16)rA3.w;
            } else if constexpr (SRC == SRC_H || SRC == SRC_CATH) {
                av0 = h0; av1 = h1;
            } else if constexpr (SRC == SRC_MULH) {
                av0[0]=(f16)((float)h0[0]*rA0.x); av0[1]=(f16)((float)h0[1]*rA0.y);
                av0[2]=(f16)((float)h0[2]*rA0.z); av0[3]=(f16)((float)h0[3]*rA0.w);
                av0[4]=(f16)((float)h0[4]*rA1.x); av0[5]=(f16)((float)h0[5]*rA1.y);
                av0[6]=(f16)((float)h0[6]*rA1.z); av0[7]=(f16)((float)h0[7]*rA1.w);
                av1[0]=(f16)((float)h1[0]*rA2.x); av1[1]=(f16)((float)h1[1]*rA2.y);
                av1[2]=(f16)((float)h1[2]*rA2.z); av1[3]=(f16)((float)h1[3]*rA2.w);
                av1[4]=(f16)((float)h1[4]*rA3.x); av1[5]=(f16)((float)h1[5]*rA3.y);
                av1[6]=(f16)((float)h1[6]*rA3.z); av1[7]=(f16)((float)h1[7]*rA3.w);
            } else if constexpr (SRC == SRC_ADDRELU) {
                av0[0]=(f16)fmaxf(rA0.x+rB0.x+rb0.x,0.f); av0[1]=(f16)fmaxf(rA0.y+rB0.y+rb0.y,0.f);
                av0[2]=(f16)fmaxf(rA0.z+rB0.z+rb0.z,0.f); av0[3]=(f16)fmaxf(rA0.w+rB0.w+rb0.w,0.f);
                av0[4]=(f16)fmaxf(rA1.x+rB1.x+rb1.x,0.f); av0[5]=(f16)fmaxf(rA1.y+rB1.y+rb1.y,0.f);
                av0[6]=(f16)fmaxf(rA1.z+rB1.z+rb1.z,0.f); av0[7]=(f16)fmaxf(rA1.w+rB1.w+rb1.w,0.f);
                av1[0]=(f16)fmaxf(rA2.x+rB2.x+rb2.x,0.f); av1[1]=(f16)fmaxf(rA2.y+rB2.y+rb2.y,0.f);
                av1[2]=(f16)fmaxf(rA2.z+rB2.z+rb2.z,0.f); av1[3]=(f16)fmaxf(rA2.w+rB2.w+rb2.w,0.f);
                av1[4]=(f16)fmaxf(rA3.x+rB3.x+rb3.x,0.f); av1[5]=(f16)fmaxf(rA3.y+rB3.y+rb3.y,0.f);
                av1[6]=(f16)fmaxf(rA3.z+rB3.z+rb3.z,0.f); av1[7]=(f16)fmaxf(rA3.w+rB3.w+rb3.w,0.f);
            }
        }
        *(f16x8*)(&Asm[b][lane_base0]) = av0;
        *(f16x8*)(&Asm[b][lane_base1]) = av1;
    };

    LOADS(0);
    COMMIT(0);
    for (int kt = 0; kt < KTILES; ++kt) {
        const int cur = kt & 1;
        if (kt + 1 < KTILES) LOADS(kt + 1);   // issue early, stays in flight
        __syncthreads();                       // buf[cur] ready, prev reads done
        f16x8 af[4][2];
        #pragma unroll
        for (int rf = 0; rf < 4; ++rf)
            #pragma unroll
            for (int kb = 0; kb < 2; ++kb)
                af[rf][kb] = *(const f16x8*)(&Asm[cur][((kb * 4 + rf) * 64 + l) * 8]);
        f16x8 bfr[4][2];
        #pragma unroll
        for (int cf = 0; cf < 4; ++cf) {
            bfr[cf][0] = *(const f16x8*)(bp[cf] + kt * 64);
            bfr[cf][1] = *(const f16x8*)(bp[cf] + kt * 64 + 32);
        }
        #pragma unroll
        for (int cf = 0; cf < 4; ++cf)
            #pragma unroll
            for (int rf = 0; rf < 4; ++rf)
                #pragma unroll
                for (int kb = 0; kb < 2; ++kb)
                    acc[rf][cf] = __builtin_amdgcn_mfma_f32_16x16x32_f16(
                        af[rf][kb], bfr[cf][kb], acc[rf][cf], 0, 0, 0);
        if (kt + 1 < KTILES) COMMIT(cur ^ 1);  // vmcnt wait lands here, after MFMA
    }

    #pragma unroll
    for (int rf = 0; rf < 4; ++rf) {
        #pragma unroll
        for (int j = 0; j < 4; ++j) {
            const int row = row0 + rf * 16 + ((l >> 4) * 4) + j;
            if (row >= NNODES) continue;
            #pragma unroll
            for (int cf = 0; cf < 4; ++cf) {
                const int col = wv * 64 + cf * 16 + (l & 15);
                float v = acc[rf][cf][j];
                if (bias) v += bias[col];
                if (ACT == ACT_RELU) v = fmaxf(v, 0.f);
                if (ACT == ACT_SIG)  v = 1.f / (1.f + expf(-v));
                if (EPI == EPI_F32 || EPI == EPI_BOTH) Cf[(size_t)row * ldc + col] = v;
                if (EPI == EPI_F16 || EPI == EPI_BOTH) Ch[(size_t)row * HDIM + col] = (f16)v;
            }
        }
    }
}

// ---------------------------------------------------------------------------
// weight pre-packs (f16 col-major)
// ---------------------------------------------------------------------------
__global__ __launch_bounds__(256) void pack_t_k(
    const float* __restrict__ W, f16* __restrict__ Wt, int K)
{
    const int idx = blockIdx.x * 256 + threadIdx.x;
    if (idx >= 256 * K) return;
    const int col = idx / K, k = idx % K;
    Wt[idx] = (f16)W[k * 256 + col];
}

__global__ __launch_bounds__(256) void pack_cat_k(
    const float* __restrict__ Wn, const float* __restrict__ Wr,
    f16* __restrict__ Wt)
{
    const int idx = blockIdx.x * 256 + threadIdx.x;
    if (idx >= 256 * 512) return;
    const int col = idx / 512, k = idx % 512;
    Wt[idx] = (f16)(k < 256 ? Wn[k * 256 + col] : Wr[(k - 256) * 256 + col]);
}

// ---------------------------------------------------------------------------
// CSR build
// ---------------------------------------------------------------------------
__global__ __launch_bounds__(256) void count_k(
    const int* __restrict__ dstIdx, int* __restrict__ counts)
{
    const int e = blockIdx.x * 256 + threadIdx.x;
    if (e < NEDGES) atomicAdd(&counts[dstIdx[e]], 1);
}

__global__ __launch_bounds__(1024) void scan_k(
    const int* __restrict__ counts, int* __restrict__ starts)
{
    __shared__ int sm[1024];
    __shared__ int s_off;
    if (threadIdx.x == 0) s_off = 0;
    __syncthreads();
    for (int base = 0; base < NNODES; base += 1024) {
        const int i = base + threadIdx.x;
        const int v = (i < NNODES) ? counts[i] : 0;
        sm[threadIdx.x] = v;
        __syncthreads();
        for (int ofs = 1; ofs < 1024; ofs <<= 1) {
            const int t = (threadIdx.x >= ofs) ? sm[threadIdx.x - ofs] : 0;
            __syncthreads();
            sm[threadIdx.x] += t;
            __syncthreads();
        }
        const int incl = sm[threadIdx.x];
        const int off = s_off;
        if (i < NNODES) starts[i] = off + incl - v;
        __syncthreads();
        if (threadIdx.x == 1023) s_off = off + incl;
        __syncthreads();
    }
    if (threadIdx.x == 0) starts[NNODES] = s_off;
}

__global__ __launch_bounds__(256) void fillcsr_k(
    const int* __restrict__ srcIdx, const int* __restrict__ dstIdx,
    int* __restrict__ cursor, int* __restrict__ csr)
{
    const int e = blockIdx.x * 256 + threadIdx.x;
    if (e >= NEDGES) return;
    const int d = dstIdx[e];
    const int p = atomicAdd(&cursor[d], 1);
    csr[p] = srcIdx[e];
}

// ---------------------------------------------------------------------------
// gather-sums: one wave per node, unroll-4 (4 row loads in flight)
// ---------------------------------------------------------------------------
__global__ __launch_bounds__(256) void gather_h_k(   // f16 -> f32
    const f16* __restrict__ rows, const int* __restrict__ csr,
    const int* __restrict__ starts, float* __restrict__ outp)
{
    const int node = (blockIdx.x * 256 + threadIdx.x) >> 6;
    const int lane = threadIdx.x & 63;
    if (node >= NNODES) return;
    const int e0 = starts[node], e1 = starts[node + 1];
    float a0=0,a1=0,a2=0,a3=0, b0=0,b1=0,b2=0,b3=0;
    int e = e0;
    for (; e + 3 < e1; e += 4) {
        const int s0=csr[e], s1=csr[e+1], s2=csr[e+2], s3=csr[e+3];
        f16x4 v0 = *(const f16x4*)(rows + (size_t)s0 * HDIM + lane * 4);
        f16x4 v1 = *(const f16x4*)(rows + (size_t)s1 * HDIM + lane * 4);
        f16x4 v2 = *(const f16x4*)(rows + (size_t)s2 * HDIM + lane * 4);
        f16x4 v3 = *(const f16x4*)(rows + (size_t)s3 * HDIM + lane * 4);
        a0 += (float)v0[0] + (float)v2[0]; a1 += (float)v0[1] + (float)v2[1];
        a2 += (float)v0[2] + (float)v2[2]; a3 += (float)v0[3] + (float)v2[3];
        b0 += (float)v1[0] + (float)v3[0]; b1 += (float)v1[1] + (float)v3[1];
        b2 += (float)v1[2] + (float)v3[2]; b3 += (float)v1[3] + (float)v3[3];
    }
    for (; e < e1; ++e) {
        const int s0 = csr[e];
        f16x4 v0 = *(const f16x4*)(rows + (size_t)s0 * HDIM + lane * 4);
        a0 += (float)v0[0]; a1 += (float)v0[1]; a2 += (float)v0[2]; a3 += (float)v0[3];
    }
    *(float4*)(outp + (size_t)node * HDIM + lane * 4) =
        make_float4(a0 + b0, a1 + b1, a2 + b2, a3 + b3);
}

__global__ __launch_bounds__(256) void gather_g_k(   // f16 -> f16
    const f16* __restrict__ rows, const int* __restrict__ csr,
    const int* __restrict__ starts, f16* __restrict__ outp)
{
    const int node = (blockIdx.x * 256 + threadIdx.x) >> 6;
    const int lane = threadIdx.x & 63;
    if (node >= NNODES) return;
    const int e0 = starts[node], e1 = starts[node + 1];
    float a0=0,a1=0,a2=0,a3=0, b0=0,b1=0,b2=0,b3=0;
    int e = e0;
    for (; e + 3 < e1; e += 4) {
        const int s0=csr[e], s1=csr[e+1], s2=csr[e+2], s3=csr[e+3];
        f16x4 v0 = *(const f16x4*)(rows + (size_t)s0 * HDIM + lane * 4);
        f16x4 v1 = *(const f16x4*)(rows + (size_t)s1 * HDIM + lane * 4);
        f16x4 v2 = *(const f16x4*)(rows + (size_t)s2 * HDIM + lane * 4);
        f16x4 v3 = *(const f16x4*)(rows + (size_t)s3 * HDIM + lane * 4);
        a0 += (float)v0[0] + (float)v2[0]; a1 += (float)v0[1] + (float)v2[1];
        a2 += (float)v0[2] + (float)v2[2]; a3 += (float)v0[3] + (float)v2[3];
        b0 += (float)v1[0] + (float)v3[0]; b1 += (float)v1[1] + (float)v3[1];
        b2 += (float)v1[2] + (float)v3[2]; b3 += (float)v1[3] + (float)v3[3];
    }
    for (; e < e1; ++e) {
        const int s0 = csr[e];
        f16x4 v0 = *(const f16x4*)(rows + (size_t)s0 * HDIM + lane * 4);
        a0 += (float)v0[0]; a1 += (float)v0[1]; a2 += (float)v0[2]; a3 += (float)v0[3];
    }
    f16x4 r;
    r[0] = (f16)(a0 + b0); r[1] = (f16)(a1 + b1);
    r[2] = (f16)(a2 + b2); r[3] = (f16)(a3 + b3);
    *(f16x4*)(outp + (size_t)node * HDIM + lane * 4) = r;
}

// ---------------------------------------------------------------------------
// xg = xh * mask -> f16
// ---------------------------------------------------------------------------
__global__ __launch_bounds__(256) void elemmul_xg_k(
    const f16* __restrict__ xh, const float* __restrict__ m,
    f16* __restrict__ o)
{
    const int t = blockIdx.x * 256 + threadIdx.x;
    const int row = t >> 6;
    const int c = (t & 63) * 4;
    if (row >= NNODES) return;
    const f16x4 xv = *(const f16x4*)(xh + (size_t)row * HDIM + c);
    const float4 mv = *(const float4*)(m + (size_t)row * HDIM + c);
    f16x4 r;
    r[0] = (f16)((float)xv[0] * mv.x); r[1] = (f16)((float)xv[1] * mv.y);
    r[2] = (f16)((float)xv[2] * mv.z); r[3] = (f16)((float)xv[3] * mv.w);
    *(f16x4*)(o + (size_t)row * HDIM + c) = r;
}

__global__ __launch_bounds__(256) void fill1_k(float* __restrict__ p, int n)
{
    const int t = blockIdx.x * 256 + threadIdx.x;
    if (t < n) p[t] = 1.0f;
}

// ---------------------------------------------------------------------------
extern "C" void kernel_launch(void* const* d_in, const int* in_sizes, int n_in,
                              void* d_out, int out_size, void* d_ws, size_t ws_size,
                              hipStream_t stream)
{
    const int*   edge   = (const int*)d_in[1];
    const int*   src    = edge;
    const int*   dst    = edge + NEDGES;
    const float* esm    = (const float*)d_in[2];
    const float* lin0_W = (const float*)d_in[4];
    const float* lin0_b = (const float*)d_in[5];
    const float* wc_W1  = (const float*)d_in[6];
    const float* wc_b1  = (const float*)d_in[7];
    const float* wc_W2  = (const float*)d_in[8];
    const float* wc_b2  = (const float*)d_in[9];
    const float* wc_W3  = (const float*)d_in[10];
    const float* wc_b3  = (const float*)d_in[11];
    const float* sc_Wn  = (const float*)d_in[12];
    const float* sc_bn  = (const float*)d_in[13];
    const float* sc_Wr  = (const float*)d_in[14];
    float* out = (float*)d_out;

    const size_t NH = (size_t)NNODES * HDIM;
    float* ws    = (float*)d_ws;
    float* aggf  = ws;                    // f32 [N,256]
    float* xw1   = ws + NH;               // f32 [N,256]
    float* maskb = ws + 2 * NH;           // f32 [N,256]
    f16*   xh    = (f16*)(ws + 3 * NH);   // f16 [N,256]  (current x)
    f16*   hnb   = xh + NH;               // f16 [N,256]  (h_nb, then xg)
    f16*   agg2  = hnb + NH;              // f16 [N,256]
    f16*   lin0t = agg2 + NH;             // 256*1280
    f16*   W2t   = lin0t + 256 * FIN;     // 4 * 65536
    f16*   W1t   = W2t + 4 * 65536;
    f16*   W3t   = W1t + 4 * 65536;
    f16*   WtC   = W3t + 4 * 65536;       // 4 * 131072
    int*   iws    = (int*)(WtC + 4 * 131072);
    int*   counts = iws;
    int*   starts = iws + NNODES;
    int*   cursor = iws + 2 * NNODES + 1;
    int*   csr    = iws + 3 * NNODES + 2;

    const dim3 blk(256);
    const int gemmGrid = (NNODES + 63) / 64;
    const int edgeGrid = (NEDGES + 255) / 256;
    const int waveGrid = (NNODES * 64) / 256;

    // ---- CSR build
    hipMemsetAsync(counts, 0, NNODES * sizeof(int), stream);
    count_k<<<edgeGrid, blk, 0, stream>>>(dst, counts);
    scan_k<<<1, 1024, 0, stream>>>(counts, starts);
    hipMemcpyAsync(cursor, starts, NNODES * sizeof(int),
                   hipMemcpyDeviceToDevice, stream);
    fillcsr_k<<<edgeGrid, blk, 0, stream>>>(src, dst, cursor, csr);

    // ---- weight packs
    pack_t_k<<<(256 * FIN + 255) / 256, blk, 0, stream>>>(lin0_W, lin0t, FIN);
    for (int i = 0; i < NLAYERS; ++i) {
        const size_t wo = (size_t)i * HDIM * HDIM;
        pack_t_k<<<256, blk, 0, stream>>>(wc_W2 + wo, W2t + i * 65536, 256);
        pack_t_k<<<256, blk, 0, stream>>>(wc_W1 + wo, W1t + i * 65536, 256);
        pack_t_k<<<256, blk, 0, stream>>>(wc_W3 + wo, W3t + i * 65536, 256);
        pack_cat_k<<<512, blk, 0, stream>>>(sc_Wn + wo, sc_Wr + wo, WtC + i * 131072);
    }

    // ---- lin0: xh = f16(esm @ W + b)
    mgemm_k<SRC_F32, EPI_F16, ACT_NONE, FIN / 64><<<gemmGrid, blk, 0, stream>>>(
        esm, FIN, nullptr, nullptr, nullptr, nullptr, lin0t, lin0_b,
        nullptr, 0, xh);

    for (int i = 0; i < NLAYERS; ++i) {
        const size_t bo = (size_t)i * HDIM;
        const f16* w2 = W2t + i * 65536;
        const f16* w1 = W1t + i * 65536;
        const f16* w3 = W3t + i * 65536;
        const f16* wc = WtC + i * 131072;

        // h_nb = xm@W2 + b2 (f16); xw1 = xm@W1 (f32); xm fused in staging
        if (i == 0) {
            mgemm_k<SRC_H, EPI_F16, ACT_NONE, 4><<<gemmGrid, blk, 0, stream>>>(
                nullptr, 0, nullptr, nullptr, xh, nullptr, w2, wc_b2 + bo,
                nullptr, 0, hnb);
            mgemm_k<SRC_H, EPI_F32, ACT_NONE, 4><<<gemmGrid, blk, 0, stream>>>(
                nullptr, 0, nullptr, nullptr, xh, nullptr, w1, nullptr,
                xw1, HDIM, nullptr);
        } else {
            mgemm_k<SRC_MULH, EPI_F16, ACT_NONE, 4><<<gemmGrid, blk, 0, stream>>>(
                nullptr, 0, maskb, nullptr, xh, nullptr, w2, wc_b2 + bo,
                nullptr, 0, hnb);
            mgemm_k<SRC_MULH, EPI_F32, ACT_NONE, 4><<<gemmGrid, blk, 0, stream>>>(
                nullptr, 0, maskb, nullptr, xh, nullptr, w1, nullptr,
                xw1, HDIM, nullptr);
        }
        // agg = segment_sum(h_nb[src], dst)
        gather_h_k<<<waveGrid, blk, 0, stream>>>(hnb, csr, starts, aggf);
        // mask = sigmoid( relu(agg + xw1 + b1) @ W3 + b3 )
        mgemm_k<SRC_ADDRELU, EPI_F32, ACT_SIG, 4><<<gemmGrid, blk, 0, stream>>>(
            aggf, HDIM, xw1, wc_b1 + bo, nullptr, nullptr, w3, wc_b3 + bo,
            maskb, HDIM, nullptr);
        // xg = xh * mask (f16, reuses hnb)
        elemmul_xg_k<<<waveGrid, blk, 0, stream>>>(xh, maskb, hnb);
        // agg2 = segment_sum(xg[src], dst)
        gather_g_k<<<waveGrid, blk, 0, stream>>>(hnb, csr, starts, agg2);
        // x_new = relu([agg2 | xh] @ [Wn;Wr] + bn) -> d_out slice i  (+ xh f16)
        mgemm_k<SRC_CATH, EPI_BOTH, ACT_RELU, 8><<<gemmGrid, blk, 0, stream>>>(
            nullptr, 0, nullptr, nullptr, agg2, xh, wc, sc_bn + bo,
            out + (size_t)i * HDIM, LDOUT, xh);
    }

    // node_mask: all true
    const size_t maskOff = (size_t)NNODES * LDOUT;
    fill1_k<<<(NNODES + 255) / 256, blk, 0, stream>>>(out + maskOff, NNODES);
}

// Round 5
// 1656.874 us; speedup vs baseline: 14.3899x; 1.0207x over previous
//
#include <hip/hip_runtime.h>

#define NNODES 50000
#define HDIM 256
#define NLAYERS 4
#define NEDGES 800000
#define FIN 1280
#define LDOUT 1024

typedef _Float16 f16;
typedef __attribute__((ext_vector_type(8))) _Float16 f16x8;
typedef __attribute__((ext_vector_type(4))) _Float16 f16x4;
typedef __attribute__((ext_vector_type(4))) float f32x4;

enum { SRC_F32 = 0, SRC_H = 1, SRC_MULH = 2, SRC_ADDRELU = 3, SRC_CATH = 4 };
enum { EPI_F32 = 0, EPI_F16 = 1, EPI_BOTH = 2, EPI_W2W1 = 3, EPI_MASKXG = 4 };
enum { ACT_NONE = 0, ACT_RELU = 1, ACT_SIG = 2 };

// ---------------------------------------------------------------------------
// Pipelined MFMA GEMM, BM=32 x BN=(CFW*64), BK=64, 256 thr = 4 waves.
// Grid = ceil(N/32) = 1563 blocks (~6/CU) for latency hiding.
// Double-buffered LDS A-tile; per-iter: issue loads(t+1) -> barrier ->
// ds_read + B-load + MFMA -> commit(t+1)  (vmcnt waits after MFMA cluster).
// Staging (A, fused elementwise):
//   SRC_F32: f32 A1(lda1)    SRC_H: f16 A3      SRC_MULH: f16 A3 * f32 A2
//   SRC_ADDRELU: relu(A1+A2+sbias[k])           SRC_CATH: k<256?A3:A4
// Epilogues:
//   EPI_W2W1: cols<256 -> Ch=f16(v+bias), cols>=256 -> Cf[col-256]=v
//   EPI_MASKXG: m=sig(v+bias); Cf=m; Ch=f16(Xh*m)
// MFMA layouts validated R3/R4 refcheck: A row=l&15,k=(l>>4)*8+j;
// B col=l&15 (col-major Wt); C/D col=l&15,row=(l>>4)*4+reg.
// ---------------------------------------------------------------------------
template<int SRC, int EPI, int ACT, int KTILES, int CFW>
__global__ __launch_bounds__(256) void mgemm_k(
    const float* __restrict__ A1, int lda1,
    const float* __restrict__ A2,
    const float* __restrict__ sbias,
    const f16*  __restrict__ A3,
    const f16*  __restrict__ A4,
    const f16*  __restrict__ Xh,
    const f16*  __restrict__ Wt,       // [CFW*64 cols][K] col-major f16
    const float* __restrict__ bias,
    float* __restrict__ Cf, int ldc,
    f16*  __restrict__ Ch)
{
    constexpr int K = KTILES * 64;
    __shared__ f16 Asm[2][2048];       // 2 x 4 KB (32 rows x 64 k)

    const int row0 = blockIdx.x * 32;
    const int tid = threadIdx.x;
    const int wv = tid >> 6;
    const int l = tid & 63;

    f32x4 acc[2][CFW] = {};

    // staging: thread t -> row r=t>>3, k-chunk kc=(t&7)*8  (8 f16 / thread)
    const int sr = tid >> 3;
    const int kc = (tid & 7) * 8;
    const int grow = row0 + sr;
    const bool rok = grow < NNODES;
    // LDS region (kb*2+rf), lane = jb*16 + (sr&15), 8 f16/slot
    const int lane_base =
        (((kc >> 5) * 2 + (sr >> 4)) * 64 + ((kc >> 3) & 3) * 16 + (sr & 15)) * 8;

    // B fragment base pointers
    const f16* bp[CFW];
    #pragma unroll
    for (int cf = 0; cf < CFW; ++cf)
        bp[cf] = Wt + (size_t)(wv * CFW * 16 + cf * 16 + (l & 15)) * K + ((l >> 4) * 8);

    float4 rA0, rA1, rB0, rB1, rb0, rb1;
    f16x8 h0;

    auto LOADS = [&](int kt) {
        if (!rok) return;
        const int k0 = kt * 64;
        if constexpr (SRC == SRC_F32) {
            const float* p = A1 + (size_t)grow * lda1 + k0 + kc;
            rA0 = *(const float4*)(p + 0);  rA1 = *(const float4*)(p + 4);
        } else if constexpr (SRC == SRC_H) {
            h0 = *(const f16x8*)(A3 + (size_t)grow * HDIM + k0 + kc);
        } else if constexpr (SRC == SRC_MULH) {
            h0 = *(const f16x8*)(A3 + (size_t)grow * HDIM + k0 + kc);
            const float* m = A2 + (size_t)grow * HDIM + k0 + kc;
            rA0 = *(const float4*)(m + 0);  rA1 = *(const float4*)(m + 4);
        } else if constexpr (SRC == SRC_ADDRELU) {
            const float* pa = A1 + (size_t)grow * HDIM + k0 + kc;
            const float* pb = A2 + (size_t)grow * HDIM + k0 + kc;
            const float* pc = sbias + k0 + kc;
            rA0 = *(const float4*)(pa + 0);  rA1 = *(const float4*)(pa + 4);
            rB0 = *(const float4*)(pb + 0);  rB1 = *(const float4*)(pb + 4);
            rb0 = *(const float4*)(pc + 0);  rb1 = *(const float4*)(pc + 4);
        } else { // SRC_CATH
            const f16* p = (k0 < HDIM)
                ? (A3 + (size_t)grow * HDIM + k0 + kc)
                : (A4 + (size_t)grow * HDIM + (k0 - HDIM) + kc);
            h0 = *(const f16x8*)p;
        }
    };

    auto COMMIT = [&](int b) {
        f16x8 av;
        #pragma unroll
        for (int i = 0; i < 8; ++i) av[i] = (f16)0.f;
        if (rok) {
            if constexpr (SRC == SRC_F32) {
                av[0]=(f16)rA0.x; av[1]=(f16)rA0.y; av[2]=(f16)rA0.z; av[3]=(f16)rA0.w;
                av[4]=(f16)rA1.x; av[5]=(f16)rA1.y; av[6]=(f16)rA1.z; av[7]=(f16)rA1.w;
            } else if constexpr (SRC == SRC_H || SRC == SRC_CATH) {
                av = h0;
            } else if constexpr (SRC == SRC_MULH) {
                av[0]=(f16)((float)h0[0]*rA0.x); av[1]=(f16)((float)h0[1]*rA0.y);
                av[2]=(f16)((float)h0[2]*rA0.z); av[3]=(f16)((float)h0[3]*rA0.w);
                av[4]=(f16)((float)h0[4]*rA1.x); av[5]=(f16)((float)h0[5]*rA1.y);
                av[6]=(f16)((float)h0[6]*rA1.z); av[7]=(f16)((float)h0[7]*rA1.w);
            } else if constexpr (SRC == SRC_ADDRELU) {
                av[0]=(f16)fmaxf(rA0.x+rB0.x+rb0.x,0.f); av[1]=(f16)fmaxf(rA0.y+rB0.y+rb0.y,0.f);
                av[2]=(f16)fmaxf(rA0.z+rB0.z+rb0.z,0.f); av[3]=(f16)fmaxf(rA0.w+rB0.w+rb0.w,0.f);
                av[4]=(f16)fmaxf(rA1.x+rB1.x+rb1.x,0.f); av[5]=(f16)fmaxf(rA1.y+rB1.y+rb1.y,0.f);
                av[6]=(f16)fmaxf(rA1.z+rB1.z+rb1.z,0.f); av[7]=(f16)fmaxf(rA1.w+rB1.w+rb1.w,0.f);
            }
        }
        *(f16x8*)(&Asm[b][lane_base]) = av;
    };

    LOADS(0);
    COMMIT(0);
    for (int kt = 0; kt < KTILES; ++kt) {
        const int cur = kt & 1;
        if (kt + 1 < KTILES) LOADS(kt + 1);
        __syncthreads();
        f16x8 af[2][2];
        #pragma unroll
        for (int rf = 0; rf < 2; ++rf)
            #pragma unroll
            for (int kb = 0; kb < 2; ++kb)
                af[rf][kb] = *(const f16x8*)(&Asm[cur][((kb * 2 + rf) * 64 + l) * 8]);
        #pragma unroll
        for (int cfb = 0; cfb < CFW / 4; ++cfb) {
            f16x8 bfr[4][2];
            #pragma unroll
            for (int c4 = 0; c4 < 4; ++c4) {
                bfr[c4][0] = *(const f16x8*)(bp[cfb * 4 + c4] + kt * 64);
                bfr[c4][1] = *(const f16x8*)(bp[cfb * 4 + c4] + kt * 64 + 32);
            }
            #pragma unroll
            for (int c4 = 0; c4 < 4; ++c4)
                #pragma unroll
                for (int rf = 0; rf < 2; ++rf)
                    #pragma unroll
                    for (int kb = 0; kb < 2; ++kb)
                        acc[rf][cfb * 4 + c4] = __builtin_amdgcn_mfma_f32_16x16x32_f16(
                            af[rf][kb], bfr[c4][kb], acc[rf][cfb * 4 + c4], 0, 0, 0);
        }
        if (kt + 1 < KTILES) COMMIT(cur ^ 1);
    }

    #pragma unroll
    for (int rf = 0; rf < 2; ++rf) {
        #pragma unroll
        for (int j = 0; j < 4; ++j) {
            const int row = row0 + rf * 16 + ((l >> 4) * 4) + j;
            if (row >= NNODES) continue;
            #pragma unroll
            for (int cf = 0; cf < CFW; ++cf) {
                const int col = wv * CFW * 16 + cf * 16 + (l & 15);
                float v = acc[rf][cf][j];
                if constexpr (EPI == EPI_W2W1) {
                    if (col < HDIM) {
                        v += bias[col];
                        Ch[(size_t)row * HDIM + col] = (f16)v;
                    } else {
                        Cf[(size_t)row * HDIM + (col - HDIM)] = v;
                    }
                } else if constexpr (EPI == EPI_MASKXG) {
                    v += bias[col];
                    v = 1.f / (1.f + expf(-v));
                    Cf[(size_t)row * HDIM + col] = v;
                    Ch[(size_t)row * HDIM + col] =
                        (f16)((float)Xh[(size_t)row * HDIM + col] * v);
                } else {
                    if (bias) v += bias[col];
                    if (ACT == ACT_RELU) v = fmaxf(v, 0.f);
                    if (ACT == ACT_SIG)  v = 1.f / (1.f + expf(-v));
                    if (EPI == EPI_F32 || EPI == EPI_BOTH) Cf[(size_t)row * ldc + col] = v;
                    if (EPI == EPI_F16 || EPI == EPI_BOTH) Ch[(size_t)row * HDIM + col] = (f16)v;
                }
            }
        }
    }
}

// ---------------------------------------------------------------------------
// weight pre-packs (f16 col-major)
// ---------------------------------------------------------------------------
__global__ __launch_bounds__(256) void pack_t_k(
    const float* __restrict__ W, f16* __restrict__ Wt, int K)
{
    const int idx = blockIdx.x * 256 + threadIdx.x;
    if (idx >= 256 * K) return;
    const int col = idx / K, k = idx % K;
    Wt[idx] = (f16)W[k * 256 + col];
}

// fused W2|W1: cols 0-255 -> W2, 256-511 -> W1, K=256
__global__ __launch_bounds__(256) void pack_w2w1_k(
    const float* __restrict__ W2, const float* __restrict__ W1,
    f16* __restrict__ Wt)
{
    const int idx = blockIdx.x * 256 + threadIdx.x;
    if (idx >= 512 * 256) return;
    const int col = idx / 256, k = idx % 256;
    Wt[idx] = (f16)(col < 256 ? W2[k * 256 + col] : W1[k * 256 + (col - 256)]);
}

// concat [Wn;Wr]: K=512
__global__ __launch_bounds__(256) void pack_cat_k(
    const float* __restrict__ Wn, const float* __restrict__ Wr,
    f16* __restrict__ Wt)
{
    const int idx = blockIdx.x * 256 + threadIdx.x;
    if (idx >= 256 * 512) return;
    const int col = idx / 512, k = idx % 512;
    Wt[idx] = (f16)(k < 256 ? Wn[k * 256 + col] : Wr[(k - 256) * 256 + col]);
}

// ---------------------------------------------------------------------------
// CSR build
// ---------------------------------------------------------------------------
__global__ __launch_bounds__(256) void count_k(
    const int* __restrict__ dstIdx, int* __restrict__ counts)
{
    const int e = blockIdx.x * 256 + threadIdx.x;
    if (e < NEDGES) atomicAdd(&counts[dstIdx[e]], 1);
}

__global__ __launch_bounds__(1024) void scan_k(
    const int* __restrict__ counts, int* __restrict__ starts)
{
    __shared__ int sm[1024];
    __shared__ int s_off;
    if (threadIdx.x == 0) s_off = 0;
    __syncthreads();
    for (int base = 0; base < NNODES; base += 1024) {
        const int i = base + threadIdx.x;
        const int v = (i < NNODES) ? counts[i] : 0;
        sm[threadIdx.x] = v;
        __syncthreads();
        for (int ofs = 1; ofs < 1024; ofs <<= 1) {
            const int t = (threadIdx.x >= ofs) ? sm[threadIdx.x - ofs] : 0;
            __syncthreads();
            sm[threadIdx.x] += t;
            __syncthreads();
        }
        const int incl = sm[threadIdx.x];
        const int off = s_off;
        if (i < NNODES) starts[i] = off + incl - v;
        __syncthreads();
        if (threadIdx.x == 1023) s_off = off + incl;
        __syncthreads();
    }
    if (threadIdx.x == 0) starts[NNODES] = s_off;
}

__global__ __launch_bounds__(256) void fillcsr_k(
    const int* __restrict__ srcIdx, const int* __restrict__ dstIdx,
    int* __restrict__ cursor, int* __restrict__ csr)
{
    const int e = blockIdx.x * 256 + threadIdx.x;
    if (e >= NEDGES) return;
    const int d = dstIdx[e];
    const int p = atomicAdd(&cursor[d], 1);
    csr[p] = srcIdx[e];
}

// ---------------------------------------------------------------------------
// gather-sums: one wave per node, unroll-4
// ---------------------------------------------------------------------------
__global__ __launch_bounds__(256) void gather_h_k(   // f16 -> f32
    const f16* __restrict__ rows, const int* __restrict__ csr,
    const int* __restrict__ starts, float* __restrict__ outp)
{
    const int node = (blockIdx.x * 256 + threadIdx.x) >> 6;
    const int lane = threadIdx.x & 63;
    if (node >= NNODES) return;
    const int e0 = starts[node], e1 = starts[node + 1];
    float a0=0,a1=0,a2=0,a3=0, b0=0,b1=0,b2=0,b3=0;
    int e = e0;
    for (; e + 3 < e1; e += 4) {
        const int s0=csr[e], s1=csr[e+1], s2=csr[e+2], s3=csr[e+3];
        f16x4 v0 = *(const f16x4*)(rows + (size_t)s0 * HDIM + lane * 4);
        f16x4 v1 = *(const f16x4*)(rows + (size_t)s1 * HDIM + lane * 4);
        f16x4 v2 = *(const f16x4*)(rows + (size_t)s2 * HDIM + lane * 4);
        f16x4 v3 = *(const f16x4*)(rows + (size_t)s3 * HDIM + lane * 4);
        a0 += (float)v0[0] + (float)v2[0]; a1 += (float)v0[1] + (float)v2[1];
        a2 += (float)v0[2] + (float)v2[2]; a3 += (float)v0[3] + (float)v2[3];
        b0 += (float)v1[0] + (float)v3[0]; b1 += (float)v1[1] + (float)v3[1];
        b2 += (float)v1[2] + (float)v3[2]; b3 += (float)v1[3] + (float)v3[3];
    }
    for (; e < e1; ++e) {
        const int s0 = csr[e];
        f16x4 v0 = *(const f16x4*)(rows + (size_t)s0 * HDIM + lane * 4);
        a0 += (float)v0[0]; a1 += (float)v0[1]; a2 += (float)v0[2]; a3 += (float)v0[3];
    }
    *(float4*)(outp + (size_t)node * HDIM + lane * 4) =
        make_float4(a0 + b0, a1 + b1, a2 + b2, a3 + b3);
}

__global__ __launch_bounds__(256) void gather_g_k(   // f16 -> f16
    const f16* __restrict__ rows, const int* __restrict__ csr,
    const int* __restrict__ starts, f16* __restrict__ outp)
{
    const int node = (blockIdx.x * 256 + threadIdx.x) >> 6;
    const int lane = threadIdx.x & 63;
    if (node >= NNODES) return;
    const int e0 = starts[node], e1 = starts[node + 1];
    float a0=0,a1=0,a2=0,a3=0, b0=0,b1=0,b2=0,b3=0;
    int e = e0;
    for (; e + 3 < e1; e += 4) {
        const int s0=csr[e], s1=csr[e+1], s2=csr[e+2], s3=csr[e+3];
        f16x4 v0 = *(const f16x4*)(rows + (size_t)s0 * HDIM + lane * 4);
        f16x4 v1 = *(const f16x4*)(rows + (size_t)s1 * HDIM + lane * 4);
        f16x4 v2 = *(const f16x4*)(rows + (size_t)s2 * HDIM + lane * 4);
        f16x4 v3 = *(const f16x4*)(rows + (size_t)s3 * HDIM + lane * 4);
        a0 += (float)v0[0] + (float)v2[0]; a1 += (float)v0[1] + (float)v2[1];
        a2 += (float)v0[2] + (float)v2[2]; a3 += (float)v0[3] + (float)v2[3];
        b0 += (float)v1[0] + (float)v3[0]; b1 += (float)v1[1] + (float)v3[1];
        b2 += (float)v1[2] + (float)v3[2]; b3 += (float)v1[3] + (float)v3[3];
    }
    for (; e < e1; ++e) {
        const int s0 = csr[e];
        f16x4 v0 = *(const f16x4*)(rows + (size_t)s0 * HDIM + lane * 4);
        a0 += (float)v0[0]; a1 += (float)v0[1]; a2 += (float)v0[2]; a3 += (float)v0[3];
    }
    f16x4 r;
    r[0] = (f16)(a0 + b0); r[1] = (f16)(a1 + b1);
    r[2] = (f16)(a2 + b2); r[3] = (f16)(a3 + b3);
    *(f16x4*)(outp + (size_t)node * HDIM + lane * 4) = r;
}

__global__ __launch_bounds__(256) void fill1_k(float* __restrict__ p, int n)
{
    const int t = blockIdx.x * 256 + threadIdx.x;
    if (t < n) p[t] = 1.0f;
}

// ---------------------------------------------------------------------------
extern "C" void kernel_launch(void* const* d_in, const int* in_sizes, int n_in,
                              void* d_out, int out_size, void* d_ws, size_t ws_size,
                              hipStream_t stream)
{
    const int*   edge   = (const int*)d_in[1];
    const int*   src    = edge;
    const int*   dst    = edge + NEDGES;
    const float* esm    = (const float*)d_in[2];
    const float* lin0_W = (const float*)d_in[4];
    const float* lin0_b = (const float*)d_in[5];
    const float* wc_W1  = (const float*)d_in[6];
    const float* wc_b1  = (const float*)d_in[7];
    const float* wc_W2  = (const float*)d_in[8];
    const float* wc_b2  = (const float*)d_in[9];
    const float* wc_W3  = (const float*)d_in[10];
    const float* wc_b3  = (const float*)d_in[11];
    const float* sc_Wn  = (const float*)d_in[12];
    const float* sc_bn  = (const float*)d_in[13];
    const float* sc_Wr  = (const float*)d_in[14];
    float* out = (float*)d_out;

    const size_t NH = (size_t)NNODES * HDIM;
    float* ws    = (float*)d_ws;
    float* aggf  = ws;                    // f32 [N,256]
    float* xw1   = ws + NH;               // f32 [N,256]
    float* maskb = ws + 2 * NH;           // f32 [N,256]
    f16*   xh    = (f16*)(ws + 3 * NH);   // f16 [N,256]  (current x)
    f16*   hnb   = xh + NH;               // f16 [N,256]  (h_nb, then xg)
    f16*   agg2  = hnb + NH;              // f16 [N,256]
    f16*   lin0t = agg2 + NH;             // 256*1280
    f16*   WF    = lin0t + 256 * FIN;     // fused W2|W1: 4 * 131072
    f16*   W3t   = WF + 4 * 131072;       // 4 * 65536
    f16*   WtC   = W3t + 4 * 65536;       // 4 * 131072
    int*   iws    = (int*)(WtC + 4 * 131072);
    int*   counts = iws;
    int*   starts = iws + NNODES;
    int*   cursor = iws + 2 * NNODES + 1;
    int*   csr    = iws + 3 * NNODES + 2;

    const dim3 blk(256);
    const int gemmGrid = (NNODES + 31) / 32;           // 1563
    const int edgeGrid = (NEDGES + 255) / 256;
    const int waveGrid = (NNODES * 64) / 256;

    // ---- CSR build
    hipMemsetAsync(counts, 0, NNODES * sizeof(int), stream);
    count_k<<<edgeGrid, blk, 0, stream>>>(dst, counts);
    scan_k<<<1, 1024, 0, stream>>>(counts, starts);
    hipMemcpyAsync(cursor, starts, NNODES * sizeof(int),
                   hipMemcpyDeviceToDevice, stream);
    fillcsr_k<<<edgeGrid, blk, 0, stream>>>(src, dst, cursor, csr);

    // ---- weight packs
    pack_t_k<<<(256 * FIN + 255) / 256, blk, 0, stream>>>(lin0_W, lin0t, FIN);
    for (int i = 0; i < NLAYERS; ++i) {
        const size_t wo = (size_t)i * HDIM * HDIM;
        pack_w2w1_k<<<512, blk, 0, stream>>>(wc_W2 + wo, wc_W1 + wo, WF + i * 131072);
        pack_t_k<<<256, blk, 0, stream>>>(wc_W3 + wo, W3t + i * 65536, 256);
        pack_cat_k<<<512, blk, 0, stream>>>(sc_Wn + wo, sc_Wr + wo, WtC + i * 131072);
    }

    // ---- lin0: xh = f16(esm @ W + b)
    mgemm_k<SRC_F32, EPI_F16, ACT_NONE, FIN / 64, 4><<<gemmGrid, blk, 0, stream>>>(
        esm, FIN, nullptr, nullptr, nullptr, nullptr, nullptr, lin0t, lin0_b,
        nullptr, 0, xh);

    for (int i = 0; i < NLAYERS; ++i) {
        const size_t bo = (size_t)i * HDIM;
        const f16* wf = WF + i * 131072;
        const f16* w3 = W3t + i * 65536;
        const f16* wc = WtC + i * 131072;

        // fused: hnb = xm@W2+b2 (f16, cols 0-255), xw1 = xm@W1 (f32, cols 256-511)
        if (i == 0) {
            mgemm_k<SRC_H, EPI_W2W1, ACT_NONE, 4, 8><<<gemmGrid, blk, 0, stream>>>(
                nullptr, 0, nullptr, nullptr, xh, nullptr, nullptr, wf, wc_b2 + bo,
                xw1, HDIM, hnb);
        } else {
            mgemm_k<SRC_MULH, EPI_W2W1, ACT_NONE, 4, 8><<<gemmGrid, blk, 0, stream>>>(
                nullptr, 0, maskb, nullptr, xh, nullptr, nullptr, wf, wc_b2 + bo,
                xw1, HDIM, hnb);
        }
        // agg = segment_sum(h_nb[src], dst)
        gather_h_k<<<waveGrid, blk, 0, stream>>>(hnb, csr, starts, aggf);
        // mask = sigmoid( relu(agg + xw1 + b1) @ W3 + b3 ); xg = xh*mask (fused)
        mgemm_k<SRC_ADDRELU, EPI_MASKXG, ACT_SIG, 4, 4><<<gemmGrid, blk, 0, stream>>>(
            aggf, HDIM, xw1, wc_b1 + bo, nullptr, nullptr, xh, w3, wc_b3 + bo,
            maskb, HDIM, hnb);
        // agg2 = segment_sum(xg[src], dst)
        gather_g_k<<<waveGrid, blk, 0, stream>>>(hnb, csr, starts, agg2);
        // x_new = relu([agg2 | xh] @ [Wn;Wr] + bn) -> d_out slice i (+ xh f16)
        mgemm_k<SRC_CATH, EPI_BOTH, ACT_RELU, 8, 4><<<gemmGrid, blk, 0, stream>>>(
            nullptr, 0, nullptr, nullptr, agg2, xh, nullptr, wc, sc_bn + bo,
            out + (size_t)i * HDIM, LDOUT, xh);
    }

    // node_mask: all true
    const size_t maskOff = (size_t)NNODES * LDOUT;
    fill1_k<<<(NNODES + 255) / 256, blk, 0, stream>>>(out + maskOff, NNODES);
}